// Round 7
// baseline (96.779 us; speedup 1.0000x reference)
//
#include <hip/hip_runtime.h>
#include <stdint.h>

// UnfoldConv1d: y[b,o,t] = bias[o] + sum_j sum_c W[o, j*512+c] * x[b,c,t-2+j]
// B=8, C=512, T=4096, OUT=512, K=3, D=1.
// v7: R1's proven 2-barrier schedule, re-tiled 256x128 block / 4 waves of
// 128x64 (21.3 vs 16 FLOP per LDS-read-byte), OPERANDS FLIPPED:
// A = x (rows=t, j-shift reuse on the big staged tile, 33KB once per c0),
// B = W (rows=o, 16KB restaged per j). D rows = t -> epilogue is one
// global_store_dwordx4 per fragment. Merged prep kernel.

typedef float    f32x4  __attribute__((ext_vector_type(4)));
typedef short    bf16x8 __attribute__((ext_vector_type(8)));

#define C_DIM   512
#define T_DIM   4096
#define TP_DIM  4104
#define OUT_DIM 512
#define KF_DIM  1536
#define B_DIM   8

__device__ __forceinline__ uint16_t f2bf(float f) {
  union { float f; uint32_t u; } v; v.f = f;
  uint32_t u = v.u;
  return (uint16_t)((u + 0x7fffu + ((u >> 16) & 1u)) >> 16);  // RNE
}

__device__ __forceinline__ void gload_lds16(const uint16_t* g, uint16_t* l) {
  __builtin_amdgcn_global_load_lds(
      (const __attribute__((address_space(1))) uint32_t*)g,
      (__attribute__((address_space(3))) uint32_t*)l, 16, 0, 0);
}

// -------- merged prep: z<8 -> x transpose tile; z==8 -> W convert ------------
__global__ __launch_bounds__(256) void prep_all(const float* __restrict__ x,
                                                const float* __restrict__ W,
                                                uint16_t* __restrict__ Wb,
                                                uint16_t* __restrict__ xp) {
  const int tid = threadIdx.x;
  if (blockIdx.z == 8) {
    // W fp32 [512][1536] -> bf16, 196608 float4 units over 260 blocks
    int flat = blockIdx.y * 65 + blockIdx.x;
    for (int i = flat * 256 + tid; i < 196608; i += 260 * 256) {
      float4 v = ((const float4*)W)[i];
      ushort4 o;
      o.x = f2bf(v.x); o.y = f2bf(v.y); o.z = f2bf(v.z); o.w = f2bf(v.w);
      ((ushort4*)Wb)[i] = o;
    }
    return;
  }
  // x fp32 [b][c][t] -> xp bf16 [b][tp][c], tp = t+2, TP=4104
  __shared__ uint16_t tile[128 * 65];  // [c 128][t 64], stride 65
  const int tp0 = blockIdx.x * 64;
  const int c0  = blockIdx.y * 128;
  const int b   = blockIdx.z;

  const int p = tid & 31;
  const int t = tp0 - 2 + p * 2;
  const bool ok = (t >= 0) && (t < T_DIM);
  #pragma unroll
  for (int it = 0; it < 16; ++it) {
    int cr = it * 8 + (tid >> 5);
    float vx = 0.f, vy = 0.f;
    if (ok) {
      const float2 v = *(const float2*)(x + (long)(b * C_DIM + c0 + cr) * T_DIM + t);
      vx = v.x; vy = v.y;
    }
    tile[cr * 65 + 2 * p]     = f2bf(vx);
    tile[cr * 65 + 2 * p + 1] = f2bf(vy);
  }
  __syncthreads();

  const int q = tid & 31;
  #pragma unroll
  for (int it = 0; it < 8; ++it) {
    int r = it * 8 + (tid >> 5);
    int tp = tp0 + r;
    if (tp < TP_DIM) {
      ushort4 val;
      val.x = tile[(4 * q + 0) * 65 + r];
      val.y = tile[(4 * q + 1) * 65 + r];
      val.z = tile[(4 * q + 2) * 65 + r];
      val.w = tile[(4 * q + 3) * 65 + r];
      *(ushort4*)(xp + (long)(b * TP_DIM + tp) * C_DIM + c0 + 4 * q) = val;
    }
  }
}

// ---------------------------- main GEMM kernel -------------------------------
// grid (T/256=16, OUT/128=4, B=8) = 512 blocks (2/CU), 256 threads, 4 waves
// as 2(t) x 2(o); wave tile 128 t x 64 o.
__global__ __launch_bounds__(256) void gemm_kernel(const uint16_t* __restrict__ xp,
                                                   const uint16_t* __restrict__ Wb,
                                                   const float* __restrict__ bias,
                                                   float* __restrict__ out) {
  __shared__ uint16_t XT[264 * 64];  // rows tp_local 0..263 (258 used), 33 KB
  __shared__ uint16_t WS[128 * 64];  // rows o_local, 16 KB, restaged per j

  const int tid  = threadIdx.x;
  const int lane = tid & 63;
  const int wid  = tid >> 6;
  const int wm   = wid >> 1;     // t-half  (0..1), 128 rows each
  const int wn   = wid & 1;      // o-half  (0..1), 64 cols each
  const int lr   = lane & 15;
  const int g    = lane >> 4;
  const int t0 = blockIdx.x * 256;
  const int o0 = blockIdx.y * 128;
  const int b  = blockIdx.z;

  const uint16_t* xbase = xp + ((long)b * TP_DIM + t0) * C_DIM;

  f32x4 acc[8][4];
  #pragma unroll
  for (int mi = 0; mi < 8; ++mi)
    #pragma unroll
    for (int ni = 0; ni < 4; ++ni)
      #pragma unroll
      for (int r = 0; r < 4; ++r) acc[mi][ni][r] = 0.0f;

  float bias_v[4];
  #pragma unroll
  for (int ni = 0; ni < 4; ++ni)
    bias_v[ni] = bias[o0 + wn * 64 + ni * 16 + lr];

  for (int c0 = 0; c0 < C_DIM; c0 += 64) {
    #pragma unroll
    for (int j = 0; j < 3; ++j) {
      __syncthreads();
      if (j == 0) {
        // stage XT: 264 rows x 8 chunks = 2112 chunks; src pre-swizzled
        #pragma unroll
        for (int it = 0; it < 8; ++it) {
          int u = it * 256 + tid;
          int row = u >> 3, ch = u & 7;
          const uint16_t* src = xbase + (long)row * C_DIM + c0 + ((ch ^ (row & 7)) << 3);
          gload_lds16(src, &XT[(it * 256 + wid * 64) * 8]);
        }
        if (tid < 64) {
          int u = 2048 + tid;
          int row = u >> 3, ch = u & 7;
          const uint16_t* src = xbase + (long)row * C_DIM + c0 + ((ch ^ (row & 7)) << 3);
          gload_lds16(src, &XT[2048 * 8]);
        }
      }
      // stage WS for this j: 128 rows x 8 chunks = 1024 chunks
      {
        const uint16_t* wbase = Wb + (long)o0 * KF_DIM + j * C_DIM + c0;
        #pragma unroll
        for (int it = 0; it < 4; ++it) {
          int u = it * 256 + tid;
          int row = u >> 3, ch = u & 7;
          const uint16_t* src = wbase + (long)row * KF_DIM + ((ch ^ (row & 7)) << 3);
          gload_lds16(src, &WS[(it * 256 + wid * 64) * 8]);
        }
      }
      __syncthreads();

      #pragma unroll
      for (int cc = 0; cc < 2; ++cc) {
        bf16x8 af[8], bf[4];
        #pragma unroll
        for (int mi = 0; mi < 8; ++mi) {
          int row = wm * 128 + mi * 16 + lr + j;   // t-row, j time-shift
          af[mi] = *(const bf16x8*)&XT[row * 64 + (((cc * 4 + g) ^ (row & 7)) << 3)];
        }
        #pragma unroll
        for (int ni = 0; ni < 4; ++ni) {
          int row = wn * 64 + ni * 16 + lr;        // o-row
          bf[ni] = *(const bf16x8*)&WS[row * 64 + (((cc * 4 + g) ^ (lr & 7)) << 3)];
        }
        #pragma unroll
        for (int mi = 0; mi < 8; ++mi)
          #pragma unroll
          for (int ni = 0; ni < 4; ++ni)
            acc[mi][ni] = __builtin_amdgcn_mfma_f32_16x16x32_bf16(
                af[mi], bf[ni], acc[mi][ni], 0, 0, 0);
      }
    }
  }

  // epilogue: D row = t (A side) = (lane>>4)*4 + r -> each lane holds 4
  // consecutive t; col = o (B side) = lane&15. One dwordx4 store per frag.
  #pragma unroll
  for (int mi = 0; mi < 8; ++mi) {
    int tcoord = t0 + wm * 128 + mi * 16 + g * 4;
    #pragma unroll
    for (int ni = 0; ni < 4; ++ni) {
      int o = o0 + wn * 64 + ni * 16 + lr;
      f32x4 v = acc[mi][ni];
      v[0] += bias_v[ni]; v[1] += bias_v[ni]; v[2] += bias_v[ni]; v[3] += bias_v[ni];
      *(f32x4*)(out + ((long)b * OUT_DIM + o) * T_DIM + tcoord) = v;
    }
  }
}

// ------------------------- naive fallback (no ws) ----------------------------
__global__ __launch_bounds__(256) void naive_kernel(const float* __restrict__ x,
                                                    const float* __restrict__ W,
                                                    const float* __restrict__ bias,
                                                    float* __restrict__ y) {
  int t = blockIdx.x * 256 + threadIdx.x;
  int o = blockIdx.y, b = blockIdx.z;
  float s = bias[o];
  #pragma unroll
  for (int j = 0; j < 3; ++j) {
    int tt = t - 2 + j;
    if (tt < 0) continue;
    const float* xr = x + (long)b * C_DIM * T_DIM + tt;
    const float* wr = W + (long)o * KF_DIM + j * C_DIM;
    float a = 0.f;
    for (int c = 0; c < C_DIM; ++c) a += wr[c] * xr[(long)c * T_DIM];
    s += a;
  }
  y[((long)b * OUT_DIM + o) * T_DIM + t] = s;
}

extern "C" void kernel_launch(void* const* d_in, const int* in_sizes, int n_in,
                              void* d_out, int out_size, void* d_ws, size_t ws_size,
                              hipStream_t stream) {
  (void)in_sizes; (void)n_in; (void)out_size;
  const float* x    = (const float*)d_in[0];
  const float* W    = (const float*)d_in[1];
  const float* bias = (const float*)d_in[2];
  float* out = (float*)d_out;

  const size_t wb_elems = (size_t)OUT_DIM * KF_DIM;          // 786432
  const size_t xp_elems = (size_t)B_DIM * TP_DIM * C_DIM;    // 16809984
  const size_t need = (wb_elems + xp_elems) * sizeof(uint16_t);

  if (ws_size < need) {  // insurance: slow but correct
    naive_kernel<<<dim3(T_DIM / 256, OUT_DIM, B_DIM), 256, 0, stream>>>(x, W, bias, out);
    return;
  }

  uint16_t* Wb = (uint16_t*)d_ws;
  uint16_t* xp = (uint16_t*)d_ws + wb_elems;

  prep_all<<<dim3(65, 4, 9), 256, 0, stream>>>(x, W, Wb, xp);
  gemm_kernel<<<dim3(16, 4, 8), 256, 0, stream>>>(xp, Wb, bias, out);
}

// Round 8
// 78.435 us; speedup vs baseline: 1.2339x; 1.2339x over previous
//
#include <hip/hip_runtime.h>
#include <stdint.h>

// UnfoldConv1d: y[b,o,t] = bias[o] + sum_j sum_c W[o, j*512+c] * x[b,c,t-2+j]
// B=8, C=512, T=4096, OUT=512, K=3, D=1.
// v8 (consolidation): R1/R5-proven GEMM (128x128 tile, 4 waves 64x64,
// 2-barrier schedule, j-reuse of XT, 906 TF measured) + merged prep kernel
// (x-transpose tiles on z=0..7, W-convert on z=8) to cut one launch gap.

typedef float    f32x4  __attribute__((ext_vector_type(4)));
typedef short    bf16x8 __attribute__((ext_vector_type(8)));

#define C_DIM   512
#define T_DIM   4096
#define TP_DIM  4104
#define OUT_DIM 512
#define KF_DIM  1536
#define B_DIM   8

__device__ __forceinline__ uint16_t f2bf(float f) {
  union { float f; uint32_t u; } v; v.f = f;
  uint32_t u = v.u;
  return (uint16_t)((u + 0x7fffu + ((u >> 16) & 1u)) >> 16);  // RNE
}

__device__ __forceinline__ void gload_lds16(const uint16_t* g, uint16_t* l) {
  __builtin_amdgcn_global_load_lds(
      (const __attribute__((address_space(1))) uint32_t*)g,
      (__attribute__((address_space(3))) uint32_t*)l, 16, 0, 0);
}

// -------- merged prep: z<8 -> x transpose tile; z==8 -> W convert ------------
__global__ __launch_bounds__(256) void prep_all(const float* __restrict__ x,
                                                const float* __restrict__ W,
                                                uint16_t* __restrict__ Wb,
                                                uint16_t* __restrict__ xp) {
  const int tid = threadIdx.x;
  if (blockIdx.z == 8) {
    // W fp32 [512][1536] -> bf16, 196608 float4 units over 260 blocks
    int flat = blockIdx.y * 65 + blockIdx.x;
    for (int i = flat * 256 + tid; i < 196608; i += 260 * 256) {
      float4 v = ((const float4*)W)[i];
      ushort4 o;
      o.x = f2bf(v.x); o.y = f2bf(v.y); o.z = f2bf(v.z); o.w = f2bf(v.w);
      ((ushort4*)Wb)[i] = o;
    }
    return;
  }
  // x fp32 [b][c][t] -> xp bf16 [b][tp][c], tp = t+2, TP=4104
  __shared__ uint16_t tile[128 * 65];  // [c 128][t 64], stride 65
  const int tp0 = blockIdx.x * 64;
  const int c0  = blockIdx.y * 128;
  const int b   = blockIdx.z;

  const int p = tid & 31;
  const int t = tp0 - 2 + p * 2;
  const bool ok = (t >= 0) && (t < T_DIM);
  #pragma unroll
  for (int it = 0; it < 16; ++it) {
    int cr = it * 8 + (tid >> 5);
    float vx = 0.f, vy = 0.f;
    if (ok) {
      const float2 v = *(const float2*)(x + (long)(b * C_DIM + c0 + cr) * T_DIM + t);
      vx = v.x; vy = v.y;
    }
    tile[cr * 65 + 2 * p]     = f2bf(vx);
    tile[cr * 65 + 2 * p + 1] = f2bf(vy);
  }
  __syncthreads();

  const int q = tid & 31;
  #pragma unroll
  for (int it = 0; it < 8; ++it) {
    int r = it * 8 + (tid >> 5);
    int tp = tp0 + r;
    if (tp < TP_DIM) {
      ushort4 val;
      val.x = tile[(4 * q + 0) * 65 + r];
      val.y = tile[(4 * q + 1) * 65 + r];
      val.z = tile[(4 * q + 2) * 65 + r];
      val.w = tile[(4 * q + 3) * 65 + r];
      *(ushort4*)(xp + (long)(b * TP_DIM + tp) * C_DIM + c0 + 4 * q) = val;
    }
  }
}

// ---------------------------- main GEMM kernel -------------------------------
// R1-proven: grid (32, 4, 8), 256 threads, 4 waves as 2x2 of 64x64.
__global__ __launch_bounds__(256) void gemm_kernel(const uint16_t* __restrict__ xp,
                                                   const uint16_t* __restrict__ Wb,
                                                   const float* __restrict__ bias,
                                                   float* __restrict__ out) {
  __shared__ uint16_t XT[136 * 64];  // [row=tp_local 0..135][c 64], swizzled
  __shared__ uint16_t WS[128 * 64];  // [row=o_local][c 64], swizzled

  const int tid  = threadIdx.x;
  const int lane = tid & 63;
  const int wid  = tid >> 6;
  const int wm   = wid >> 1;     // wave row (0..1)
  const int wn   = wid & 1;      // wave col (0..1)
  const int t0 = blockIdx.x * 128;
  const int o0 = blockIdx.y * 128;
  const int b  = blockIdx.z;

  f32x4 acc[4][4];
  #pragma unroll
  for (int mi = 0; mi < 4; ++mi)
    #pragma unroll
    for (int ni = 0; ni < 4; ++ni)
      #pragma unroll
      for (int r = 0; r < 4; ++r) acc[mi][ni][r] = 0.0f;

  const uint16_t* xbase = xp + ((long)b * TP_DIM + t0) * C_DIM;
  const int g = lane >> 4;  // k-group 0..3 (8 consecutive k each)

  for (int c0 = 0; c0 < C_DIM; c0 += 64) {
    #pragma unroll
    for (int j = 0; j < 3; ++j) {
      __syncthreads();
      if (j == 0) {
        // stage XT: 136 rows x 8 chunks(16B); src chunk pre-swizzled
        #pragma unroll
        for (int it = 0; it < 4; ++it) {
          int u = it * 256 + tid;
          int row = u >> 3, ch = u & 7;
          const uint16_t* src = xbase + (long)row * C_DIM + c0 + ((ch ^ (row & 7)) << 3);
          gload_lds16(src, &XT[(it * 256 + wid * 64) * 8]);
        }
        if (tid < 64) {
          int u = 1024 + tid;
          int row = u >> 3, ch = u & 7;
          const uint16_t* src = xbase + (long)row * C_DIM + c0 + ((ch ^ (row & 7)) << 3);
          gload_lds16(src, &XT[1024 * 8]);
        }
      }
      // stage WS for this j: 128 rows x 8 chunks
      {
        const uint16_t* wbase = Wb + (long)o0 * KF_DIM + j * C_DIM + c0;
        #pragma unroll
        for (int it = 0; it < 4; ++it) {
          int u = it * 256 + tid;
          int row = u >> 3, ch = u & 7;
          const uint16_t* src = wbase + (long)row * KF_DIM + ((ch ^ (row & 7)) << 3);
          gload_lds16(src, &WS[(it * 256 + wid * 64) * 8]);
        }
      }
      __syncthreads();

      #pragma unroll
      for (int cc = 0; cc < 2; ++cc) {
        bf16x8 af[4], bfr[4];
        #pragma unroll
        for (int mi = 0; mi < 4; ++mi) {
          int row = wm * 64 + mi * 16 + (lane & 15);
          int chs = (cc * 4 + g) ^ (row & 7);
          af[mi] = *(const bf16x8*)&WS[row * 64 + chs * 8];
        }
        #pragma unroll
        for (int ni = 0; ni < 4; ++ni) {
          int row = wn * 64 + ni * 16 + (lane & 15) + j;  // tp_local = tn + j
          int chs = (cc * 4 + g) ^ (row & 7);
          bfr[ni] = *(const bf16x8*)&XT[row * 64 + chs * 8];
        }
        #pragma unroll
        for (int mi = 0; mi < 4; ++mi)
          #pragma unroll
          for (int ni = 0; ni < 4; ++ni)
            acc[mi][ni] = __builtin_amdgcn_mfma_f32_16x16x32_bf16(
                af[mi], bfr[ni], acc[mi][ni], 0, 0, 0);
      }
    }
  }

  // epilogue: D layout col=lane&15 (t), row=(lane>>4)*4+r (o)  [m89-verified]
  #pragma unroll
  for (int mi = 0; mi < 4; ++mi) {
    int orow = o0 + wm * 64 + mi * 16 + (lane >> 4) * 4;
    #pragma unroll
    for (int ni = 0; ni < 4; ++ni) {
      int t = t0 + wn * 64 + ni * 16 + (lane & 15);
      float* op = out + ((long)b * OUT_DIM + orow) * T_DIM + t;
      #pragma unroll
      for (int r = 0; r < 4; ++r)
        op[(long)r * T_DIM] = acc[mi][ni][r] + bias[orow + r];
    }
  }
}

// ------------------------- naive fallback (no ws) ----------------------------
__global__ __launch_bounds__(256) void naive_kernel(const float* __restrict__ x,
                                                    const float* __restrict__ W,
                                                    const float* __restrict__ bias,
                                                    float* __restrict__ y) {
  int t = blockIdx.x * 256 + threadIdx.x;
  int o = blockIdx.y, b = blockIdx.z;
  float s = bias[o];
  #pragma unroll
  for (int j = 0; j < 3; ++j) {
    int tt = t - 2 + j;
    if (tt < 0) continue;
    const float* xr = x + (long)b * C_DIM * T_DIM + tt;
    const float* wr = W + (long)o * KF_DIM + j * C_DIM;
    float a = 0.f;
    for (int c = 0; c < C_DIM; ++c) a += wr[c] * xr[(long)c * T_DIM];
    s += a;
  }
  y[((long)b * OUT_DIM + o) * T_DIM + t] = s;
}

extern "C" void kernel_launch(void* const* d_in, const int* in_sizes, int n_in,
                              void* d_out, int out_size, void* d_ws, size_t ws_size,
                              hipStream_t stream) {
  (void)in_sizes; (void)n_in; (void)out_size;
  const float* x    = (const float*)d_in[0];
  const float* W    = (const float*)d_in[1];
  const float* bias = (const float*)d_in[2];
  float* out = (float*)d_out;

  const size_t wb_elems = (size_t)OUT_DIM * KF_DIM;          // 786432
  const size_t xp_elems = (size_t)B_DIM * TP_DIM * C_DIM;    // 16809984
  const size_t need = (wb_elems + xp_elems) * sizeof(uint16_t);

  if (ws_size < need) {  // insurance: slow but correct
    naive_kernel<<<dim3(T_DIM / 256, OUT_DIM, B_DIM), 256, 0, stream>>>(x, W, bias, out);
    return;
  }

  uint16_t* Wb = (uint16_t*)d_ws;
  uint16_t* xp = (uint16_t*)d_ws + wb_elems;

  prep_all<<<dim3(65, 4, 9), 256, 0, stream>>>(x, W, Wb, xp);
  gemm_kernel<<<dim3(32, 4, 8), 256, 0, stream>>>(xp, Wb, bias, out);
}